// Round 1
// baseline (1820.028 us; speedup 1.0000x reference)
//
#include <hip/hip_runtime.h>
#include <cmath>

#define D_MODEL 768
#define D_STATE 8
#define D_CONV  4
#define D_INNER 1536
#define DT_RANK 48
#define NB 8
#define NS 1024
#define MROWS (NB*NS)   // 8192

__device__ __forceinline__ float sigmoidf_(float x) { return 1.f / (1.f + __expf(-x)); }
__device__ __forceinline__ float softplusf_(float x) {
    return log1pf(__expf(-fabsf(x))) + fmaxf(x, 0.f);
}

// C[M,N] = A[M,K] (row stride lda) * B[N,K]^T (row stride ldb), C row stride ldc.
// EPI==0: plain store. EPI==1: C = softplus(acc + bias[col]) + 1e-4.
// Requires: M%64==0, N%64==0, K%16==0, lda/ldb/ldc%4==0 (float4 alignment).
template<int EPI>
__global__ __launch_bounds__(256) void gemm_nt(const float* __restrict__ A,
                                               const float* __restrict__ B,
                                               const float* __restrict__ bias,
                                               float* __restrict__ C,
                                               int M, int N, int K,
                                               int lda, int ldb, int ldc)
{
    __shared__ float As[16][65];
    __shared__ float Bs[16][65];
    const int bm = blockIdx.y * 64;
    const int bn = blockIdx.x * 64;
    const int tid = threadIdx.x;
    const int r  = tid >> 2;          // 0..63 : row within tile for staging
    const int kk = (tid & 3) << 2;    // 0,4,8,12 : k-chunk for staging
    const int tr = tid >> 4;          // 0..15 : micro-tile row group
    const int tc = tid & 15;          // 0..15 : micro-tile col group

    float acc[4][4] = {};

    for (int k0 = 0; k0 < K; k0 += 16) {
        float4 av = *(const float4*)(A + (size_t)(bm + r) * lda + k0 + kk);
        float4 bv = *(const float4*)(B + (size_t)(bn + r) * ldb + k0 + kk);
        As[kk + 0][r] = av.x; As[kk + 1][r] = av.y; As[kk + 2][r] = av.z; As[kk + 3][r] = av.w;
        Bs[kk + 0][r] = bv.x; Bs[kk + 1][r] = bv.y; Bs[kk + 2][r] = bv.z; Bs[kk + 3][r] = bv.w;
        __syncthreads();
        #pragma unroll
        for (int k = 0; k < 16; ++k) {
            float a0 = As[k][tr * 4 + 0], a1 = As[k][tr * 4 + 1];
            float a2 = As[k][tr * 4 + 2], a3 = As[k][tr * 4 + 3];
            float b0 = Bs[k][tc * 4 + 0], b1 = Bs[k][tc * 4 + 1];
            float b2 = Bs[k][tc * 4 + 2], b3 = Bs[k][tc * 4 + 3];
            acc[0][0] += a0 * b0; acc[0][1] += a0 * b1; acc[0][2] += a0 * b2; acc[0][3] += a0 * b3;
            acc[1][0] += a1 * b0; acc[1][1] += a1 * b1; acc[1][2] += a1 * b2; acc[1][3] += a1 * b3;
            acc[2][0] += a2 * b0; acc[2][1] += a2 * b1; acc[2][2] += a2 * b2; acc[2][3] += a2 * b3;
            acc[3][0] += a3 * b0; acc[3][1] += a3 * b1; acc[3][2] += a3 * b2; acc[3][3] += a3 * b3;
        }
        __syncthreads();
    }

    #pragma unroll
    for (int i = 0; i < 4; ++i) {
        const int row = bm + tr * 4 + i;
        const int col = bn + tc * 4;
        float4 v;
        float vv[4];
        #pragma unroll
        for (int j = 0; j < 4; ++j) {
            float t = acc[i][j];
            if (EPI == 1) t = softplusf_(t + bias[col + j]) + 1e-4f;
            vv[j] = t;
        }
        v.x = vv[0]; v.y = vv[1]; v.z = vv[2]; v.w = vv[3];
        *(float4*)(C + (size_t)row * ldc + col) = v;
    }
}

// Depthwise causal conv (4 taps) + bias + SiLU.
// Reads x_part = xz[:, :, 0:D_INNER] (row stride 2*D_INNER); writes xc (row stride D_INNER).
__global__ __launch_bounds__(256) void conv_silu(const float* __restrict__ xz,
                                                 const float* __restrict__ cw,
                                                 const float* __restrict__ cb,
                                                 float* __restrict__ xc)
{
    const int idx = blockIdx.x * 256 + threadIdx.x;   // over MROWS*D_INNER
    const int i  = idx % D_INNER;
    const int bs = idx / D_INNER;      // b*NS + s
    const int s  = bs & (NS - 1);
    float acc = cb[i];
    #pragma unroll
    for (int k = 0; k < 4; ++k) {
        const int sp = s - 3 + k;
        if (sp >= 0)
            acc += xz[(size_t)(bs - 3 + k) * (2 * D_INNER) + i] * cw[i * 4 + k];
    }
    xc[(size_t)bs * D_INNER + i] = acc * sigmoidf_(acc);
}

// tanh in place on dtbc columns 48..63 (b_term, c_term).
__global__ __launch_bounds__(256) void tanh_bc(float* __restrict__ dtbc)
{
    const int idx = blockIdx.x * 256 + threadIdx.x;   // over MROWS*16
    const int row = idx >> 4;
    const int c   = idx & 15;
    float* p = dtbc + (size_t)row * 64 + DT_RANK + c;
    *p = tanhf(*p);
}

// Sequential selective scan, one thread per (b, i). 8 states in registers.
// Fused epilogue: y_mixed = (state.c + D*x) * silu(z), written over xz[:, :, 0:D_INNER].
__global__ __launch_bounds__(256) void scan_fused(const float* __restrict__ xc,
                                                  const float* __restrict__ dt,
                                                  const float* __restrict__ dtbc,
                                                  const float* __restrict__ A_log,
                                                  const float* __restrict__ D_skip,
                                                  float* __restrict__ xz)
{
    const int idx = blockIdx.x * 256 + threadIdx.x;   // 0..NB*D_INNER-1
    const int b = idx / D_INNER;
    const int i = idx % D_INNER;

    float a[8];
    #pragma unroll
    for (int n = 0; n < 8; ++n) a[n] = -__expf(A_log[i * 8 + n]);
    const float dsk = D_skip[i];

    float st[8] = {};
    const size_t rb = (size_t)b * NS;
    for (int s = 0; s < NS; ++s) {
        const size_t row = rb + s;
        const float xv  = xc[row * D_INNER + i];
        const float dtv = dt[row * D_INNER + i];
        const float* bc = dtbc + row * 64 + DT_RANK;  // [0..7]=b, [8..15]=c (already tanh'ed)
        float accy = 0.f;
        #pragma unroll
        for (int n = 0; n < 8; ++n) {
            const float da = __expf(dtv * a[n]);
            st[n] = da * st[n] + (1.f - da) * bc[n] * xv;
            accy += st[n] * bc[8 + n];
        }
        const float y  = accy + dsk * xv;
        const float zv = xz[row * (2 * D_INNER) + D_INNER + i];
        xz[row * (2 * D_INNER) + i] = y * (zv * sigmoidf_(zv));
    }
}

extern "C" void kernel_launch(void* const* d_in, const int* in_sizes, int n_in,
                              void* d_out, int out_size, void* d_ws, size_t ws_size,
                              hipStream_t stream) {
    const float* x      = (const float*)d_in[0];
    const float* W_in   = (const float*)d_in[1];
    const float* conv_w = (const float*)d_in[2];
    const float* conv_b = (const float*)d_in[3];
    const float* W_x    = (const float*)d_in[4];
    const float* W_dt   = (const float*)d_in[5];
    const float* b_dt   = (const float*)d_in[6];
    const float* A_log  = (const float*)d_in[7];
    const float* D_skip = (const float*)d_in[8];
    const float* W_out  = (const float*)d_in[9];
    float* out = (float*)d_out;

    float* ws   = (float*)d_ws;
    float* xz   = ws;                                    // [8192][3072]
    float* xc   = xz   + (size_t)MROWS * 2 * D_INNER;    // [8192][1536]
    float* dtbc = xc   + (size_t)MROWS * D_INNER;        // [8192][64]
    float* dtb  = dtbc + (size_t)MROWS * 64;             // [8192][1536]

    dim3 blk(256);

    // 1) xz = x @ W_in^T   (M=8192, N=3072, K=768)
    gemm_nt<0><<<dim3(3072 / 64, MROWS / 64), blk, 0, stream>>>(
        x, W_in, nullptr, xz, MROWS, 2 * D_INNER, D_MODEL, D_MODEL, D_MODEL, 2 * D_INNER);

    // 2) depthwise conv + silu -> xc
    conv_silu<<<dim3((MROWS * D_INNER) / 256), blk, 0, stream>>>(xz, conv_w, conv_b, xc);

    // 3) dtbc = xc @ W_x^T  (N=64, K=1536)
    gemm_nt<0><<<dim3(64 / 64, MROWS / 64), blk, 0, stream>>>(
        xc, W_x, nullptr, dtbc, MROWS, 64, D_INNER, D_INNER, D_INNER, 64);

    // 4) tanh on b/c columns
    tanh_bc<<<dim3((MROWS * 16) / 256), blk, 0, stream>>>(dtbc);

    // 5) dt = softplus(dt_part @ W_dt^T + b_dt) + 1e-4   (K=48, lda=64)
    gemm_nt<1><<<dim3(D_INNER / 64, MROWS / 64), blk, 0, stream>>>(
        dtbc, W_dt, b_dt, dtb, MROWS, D_INNER, DT_RANK, 64, DT_RANK, D_INNER);

    // 6) scan + mix epilogue; writes y_mixed over xz[:, :, 0:D_INNER]
    scan_fused<<<dim3((NB * D_INNER) / 256), blk, 0, stream>>>(
        xc, dtb, dtbc, A_log, D_skip, xz);

    // 7) out = y_mixed @ W_out^T  (lda=3072 reads strided first half of xz)
    gemm_nt<0><<<dim3(D_MODEL / 64, MROWS / 64), blk, 0, stream>>>(
        xz, W_out, nullptr, out, MROWS, D_MODEL, D_INNER, 2 * D_INNER, D_INNER, D_MODEL);
}

// Round 4
// 1014.336 us; speedup vs baseline: 1.7943x; 1.7943x over previous
//
#include <hip/hip_runtime.h>
#include <cmath>

#define D_MODEL 768
#define D_STATE 8
#define D_CONV  4
#define D_INNER 1536
#define DT_RANK 48
#define NB 8
#define NS 1024
#define MROWS (NB*NS)   // 8192

typedef short s16x8 __attribute__((ext_vector_type(8)));
typedef float f32x4 __attribute__((ext_vector_type(4)));

__device__ __forceinline__ float sigmoidf_(float x) { return 1.f / (1.f + __expf(-x)); }
__device__ __forceinline__ float softplusf_(float x) {
    return log1pf(__expf(-fabsf(x))) + fmaxf(x, 0.f);
}
__device__ __forceinline__ unsigned short f2bf(float v) {   // RNE float->bf16
    unsigned u = __float_as_uint(v);
    u += 0x7FFFu + ((u >> 16) & 1u);
    return (unsigned short)(u >> 16);
}
__device__ __forceinline__ float bf2f(unsigned short s) {
    return __uint_as_float(((unsigned)s) << 16);
}

// ---------------- split-bf16 [hi | lo] conversion (2K shorts per row) ----------------
__global__ __launch_bounds__(256) void split2(const float* __restrict__ src,
                                              unsigned short* __restrict__ dst,
                                              int rows, int K)
{
    int idx = blockIdx.x * 256 + threadIdx.x;
    if (idx >= rows * K) return;
    int r = idx / K, k = idx - r * K;
    float v = src[idx];
    unsigned short h  = f2bf(v);
    unsigned short lo = f2bf(v - bf2f(h));
    unsigned short* d = dst + (size_t)r * 2 * K + k;
    d[0] = h;
    d[K] = lo;
}

// ---------------- MFMA GEMM: C[M,N] = A*B^T in 3-term split-bf16 ----------------
// A stored [hi|lo] (2K shorts, row stride lda); virtual K' = 3K with
// A channels [hi|lo|hi]  -> kA = k0<2K ? k0 : k0-2K
// B channels [hi|hi|lo]  -> kB = k0<K  ? k0 : k0-K
// 128x128 tile, BK=32 shorts, 4 waves (each 64x64 = 4x4 frags of 16x16x32 bf16).
// REGISTER-STAGED LDS (no global_load_lds): plain __shared__ stores are
// compiler-ordered against __syncthreads — removes the replay race.
// LDS rows padded to 40 shorts (80 B): 16B-aligned rows, ~2-way bank aliasing (free).
__global__ __launch_bounds__(256) void gemm_mfma_nt(const unsigned short* __restrict__ A,
                                                    int lda,
                                                    const unsigned short* __restrict__ B,
                                                    int ldb,
                                                    float* __restrict__ C,
                                                    int ldc, int K)
{
    __shared__ unsigned short Ash[128][40];   // 10 KB
    __shared__ unsigned short Bsh[128][40];   // 10 KB
    const int tid = threadIdx.x;
    const int w  = tid >> 6;            // wave 0..3
    const int l  = tid & 63;
    const int wr = w >> 1, wc = w & 1;  // wave -> 64x64 quadrant
    const int lr = l & 15, lg = l >> 4;
    const long bm = (long)blockIdx.y * 128;
    const long bn = (long)blockIdx.x * 128;

    // staging: thread t loads 32 B of A and 32 B of B: row = t>>1, half = t&1
    const int srow  = tid >> 1;
    const int shalf = tid & 1;          // 16-short (32 B) half of the 32-short row chunk
    const unsigned short* gA = A + (size_t)(bm + srow) * lda + shalf * 16;
    const unsigned short* gB = B + (size_t)(bn + srow) * ldb + shalf * 16;
    unsigned short* lA = &Ash[srow][shalf * 16];
    unsigned short* lB = &Bsh[srow][shalf * 16];

    f32x4 acc[4][4] = {};

    const int K3 = 3 * K;
    for (int k0 = 0; k0 < K3; k0 += 32) {
        const int kA = (k0 < 2 * K) ? k0 : k0 - 2 * K;
        const int kB = (k0 < K) ? k0 : k0 - K;
        // global -> regs (issued early; latency overlaps the barrier wait)
        s16x8 ra0 = *(const s16x8*)(gA + kA);
        s16x8 ra1 = *(const s16x8*)(gA + kA + 8);
        s16x8 rb0 = *(const s16x8*)(gB + kB);
        s16x8 rb1 = *(const s16x8*)(gB + kB + 8);
        __syncthreads();                  // all waves done reading previous tile
        *(s16x8*)(lA)     = ra0;
        *(s16x8*)(lA + 8) = ra1;
        *(s16x8*)(lB)     = rb0;
        *(s16x8*)(lB + 8) = rb1;
        __syncthreads();                  // tile ready
        s16x8 af[4], bfr[4];
        #pragma unroll
        for (int m = 0; m < 4; ++m) {
            const int arow = wr * 64 + m * 16 + lr;
            const int brow = wc * 64 + m * 16 + lr;
            af[m]  = *(const s16x8*)(&Ash[arow][lg * 8]);
            bfr[m] = *(const s16x8*)(&Bsh[brow][lg * 8]);
        }
        #pragma unroll
        for (int m = 0; m < 4; ++m)
            #pragma unroll
            for (int n = 0; n < 4; ++n)
                acc[m][n] = __builtin_amdgcn_mfma_f32_16x16x32_bf16(af[m], bfr[n], acc[m][n], 0, 0, 0);
    }

    // C/D layout: col = lane&15, row = (lane>>4)*4 + reg
    #pragma unroll
    for (int m = 0; m < 4; ++m) {
        #pragma unroll
        for (int n = 0; n < 4; ++n) {
            const size_t row0 = bm + wr * 64 + m * 16 + lg * 4;
            const int    col  = bn + wc * 64 + n * 16 + lr;
            #pragma unroll
            for (int r = 0; r < 4; ++r)
                C[(row0 + r) * (size_t)ldc + col] = acc[m][n][r];
        }
    }
}

// ---------------- fp32 vector GEMM (two small GEMMs) ----------------
template<int EPI>
__global__ __launch_bounds__(256) void gemm_nt(const float* __restrict__ A,
                                               const float* __restrict__ B,
                                               const float* __restrict__ bias,
                                               float* __restrict__ C,
                                               int M, int N, int K,
                                               int lda, int ldb, int ldc)
{
    __shared__ float As[16][65];
    __shared__ float Bs[16][65];
    const int bm = blockIdx.y * 64;
    const int bn = blockIdx.x * 64;
    const int tid = threadIdx.x;
    const int r  = tid >> 2;
    const int kk = (tid & 3) << 2;
    const int tr = tid >> 4;
    const int tc = tid & 15;

    float acc[4][4] = {};

    for (int k0 = 0; k0 < K; k0 += 16) {
        float4 av = *(const float4*)(A + (size_t)(bm + r) * lda + k0 + kk);
        float4 bv = *(const float4*)(B + (size_t)(bn + r) * ldb + k0 + kk);
        As[kk + 0][r] = av.x; As[kk + 1][r] = av.y; As[kk + 2][r] = av.z; As[kk + 3][r] = av.w;
        Bs[kk + 0][r] = bv.x; Bs[kk + 1][r] = bv.y; Bs[kk + 2][r] = bv.z; Bs[kk + 3][r] = bv.w;
        __syncthreads();
        #pragma unroll
        for (int k = 0; k < 16; ++k) {
            float a0 = As[k][tr * 4 + 0], a1 = As[k][tr * 4 + 1];
            float a2 = As[k][tr * 4 + 2], a3 = As[k][tr * 4 + 3];
            float b0 = Bs[k][tc * 4 + 0], b1 = Bs[k][tc * 4 + 1];
            float b2 = Bs[k][tc * 4 + 2], b3 = Bs[k][tc * 4 + 3];
            acc[0][0] += a0 * b0; acc[0][1] += a0 * b1; acc[0][2] += a0 * b2; acc[0][3] += a0 * b3;
            acc[1][0] += a1 * b0; acc[1][1] += a1 * b1; acc[1][2] += a1 * b2; acc[1][3] += a1 * b3;
            acc[2][0] += a2 * b0; acc[2][1] += a2 * b1; acc[2][2] += a2 * b2; acc[2][3] += a2 * b3;
            acc[3][0] += a3 * b0; acc[3][1] += a3 * b1; acc[3][2] += a3 * b2; acc[3][3] += a3 * b3;
        }
        __syncthreads();
    }

    #pragma unroll
    for (int i = 0; i < 4; ++i) {
        const int row = bm + tr * 4 + i;
        const int col = bn + tc * 4;
        float vv[4];
        #pragma unroll
        for (int j = 0; j < 4; ++j) {
            float t = acc[i][j];
            if (EPI == 1) t = softplusf_(t + bias[col + j]) + 1e-4f;
            vv[j] = t;
        }
        float4 v; v.x = vv[0]; v.y = vv[1]; v.z = vv[2]; v.w = vv[3];
        *(float4*)(C + (size_t)row * ldc + col) = v;
    }
}

// ---------------- depthwise causal conv + SiLU ----------------
__global__ __launch_bounds__(256) void conv_silu(const float* __restrict__ xz,
                                                 const float* __restrict__ cw,
                                                 const float* __restrict__ cb,
                                                 float* __restrict__ xc)
{
    const int idx = blockIdx.x * 256 + threadIdx.x;
    const int i  = idx % D_INNER;
    const int bs = idx / D_INNER;
    const int s  = bs & (NS - 1);
    float acc = cb[i];
    #pragma unroll
    for (int k = 0; k < 4; ++k) {
        const int sp = s - 3 + k;
        if (sp >= 0)
            acc += xz[(size_t)(bs - 3 + k) * (2 * D_INNER) + i] * cw[i * 4 + k];
    }
    xc[(size_t)bs * D_INNER + i] = acc * sigmoidf_(acc);
}

__global__ __launch_bounds__(256) void tanh_bc(float* __restrict__ dtbc)
{
    const int idx = blockIdx.x * 256 + threadIdx.x;
    const int row = idx >> 4;
    const int c   = idx & 15;
    float* p = dtbc + (size_t)row * 64 + DT_RANK + c;
    *p = tanhf(*p);
}

// ---------------- selective scan; epilogue writes y [hi|lo] bf16 over xz x-half ----------------
// y3 row r lives at ((ushort*)xz) + r*6144: [hi(1536) | lo(1536)] (x_part bytes, dead).
__global__ __launch_bounds__(256) void scan_fused(const float* __restrict__ xc,
                                                  const float* __restrict__ dt,
                                                  const float* __restrict__ dtbc,
                                                  const float* __restrict__ A_log,
                                                  const float* __restrict__ D_skip,
                                                  float* xz)
{
    const int idx = blockIdx.x * 256 + threadIdx.x;   // 0..NB*D_INNER-1
    const int b = idx / D_INNER;
    const int i = idx % D_INNER;

    float a[8];
    #pragma unroll
    for (int n = 0; n < 8; ++n) a[n] = -__expf(A_log[i * 8 + n]);
    const float dsk = D_skip[i];

    unsigned short* y3 = (unsigned short*)xz;
    float st[8] = {};
    const size_t rb = (size_t)b * NS;
    for (int s = 0; s < NS; ++s) {
        const size_t row = rb + s;
        const float xv  = xc[row * D_INNER + i];
        const float dtv = dt[row * D_INNER + i];
        const float* bc = dtbc + row * 64 + DT_RANK;
        float accy = 0.f;
        #pragma unroll
        for (int n = 0; n < 8; ++n) {
            const float da = __expf(dtv * a[n]);
            st[n] = da * st[n] + (1.f - da) * bc[n] * xv;
            accy += st[n] * bc[8 + n];
        }
        const float y  = accy + dsk * xv;
        const float zv = xz[row * (2 * D_INNER) + D_INNER + i];
        const float ym = y * (zv * sigmoidf_(zv));
        unsigned short h  = f2bf(ym);
        unsigned short lo = f2bf(ym - bf2f(h));
        unsigned short* d = y3 + row * (size_t)(4 * D_INNER) + i;  // row stride 6144 shorts
        d[0]       = h;
        d[D_INNER] = lo;
    }
}

extern "C" void kernel_launch(void* const* d_in, const int* in_sizes, int n_in,
                              void* d_out, int out_size, void* d_ws, size_t ws_size,
                              hipStream_t stream) {
    const float* x      = (const float*)d_in[0];
    const float* W_in   = (const float*)d_in[1];
    const float* conv_w = (const float*)d_in[2];
    const float* conv_b = (const float*)d_in[3];
    const float* W_x    = (const float*)d_in[4];
    const float* W_dt   = (const float*)d_in[5];
    const float* b_dt   = (const float*)d_in[6];
    const float* A_log  = (const float*)d_in[7];
    const float* D_skip = (const float*)d_in[8];
    const float* W_out  = (const float*)d_in[9];
    float* out = (float*)d_out;

    // Workspace: EXACTLY the round-1 footprint (203,423,744 B, proven <= ws_size).
    char* wsb = (char*)d_ws;
    float* xz   = (float*)(wsb);                    // [8192][3072] f32 (y3 bf16 reuses x-half)
    float* xc   = (float*)(wsb + 100663296);        // [8192][1536] f32
    float* dtbc = (float*)(wsb + 150994944);        // [8192][64]   f32
    float* dtb  = (float*)(wsb + 153092096);        // [8192][1536] f32  (aliased below)
    // dtb region aliases (disjoint lifetimes, stream-ordered):
    unsigned short* x3  = (unsigned short*)(wsb + 153092096);  // [8192][1536] bf16 hi|lo (dead before dtb)
    unsigned short* W3  = (unsigned short*)(wsb + 178257920);  // [3072][1536] bf16 hi|lo (dead before dtb)
    unsigned short* Wo3 = (unsigned short*)(wsb + 153092096);  // [768][3072]  bf16 hi|lo (born after dtb dies)
    unsigned short* y3  = (unsigned short*)xz;                 // [8192] rows @ stride 6144 shorts

    dim3 blk(256);

    // 0) split-bf16 conversions for GEMM1
    split2<<<dim3((MROWS * D_MODEL + 255) / 256), blk, 0, stream>>>(x, x3, MROWS, D_MODEL);
    split2<<<dim3((2 * D_INNER * D_MODEL + 255) / 256), blk, 0, stream>>>(W_in, W3, 2 * D_INNER, D_MODEL);

    // 1) xz = x @ W_in^T via MFMA (virtual K' = 3*768)
    gemm_mfma_nt<<<dim3(3072 / 128, MROWS / 128), blk, 0, stream>>>(
        x3, 2 * D_MODEL, W3, 2 * D_MODEL, xz, 3072, D_MODEL);

    // 2) depthwise conv + silu -> xc
    conv_silu<<<dim3((MROWS * D_INNER) / 256), blk, 0, stream>>>(xz, conv_w, conv_b, xc);

    // 3) dtbc = xc @ W_x^T  (N=64, K=1536) — fp32 vector
    gemm_nt<0><<<dim3(64 / 64, MROWS / 64), blk, 0, stream>>>(
        xc, W_x, nullptr, dtbc, MROWS, 64, D_INNER, D_INNER, D_INNER, 64);

    // 4) tanh on b/c columns
    tanh_bc<<<dim3((MROWS * 16) / 256), blk, 0, stream>>>(dtbc);

    // 5) dt = softplus(dt_part @ W_dt^T + b_dt) + 1e-4 — fp32 vector
    gemm_nt<1><<<dim3(D_INNER / 64, MROWS / 64), blk, 0, stream>>>(
        dtbc, W_dt, b_dt, dtb, MROWS, D_INNER, DT_RANK, 64, DT_RANK, D_INNER);

    // 6) scan + mix epilogue -> y3 (bf16 hi|lo over xz x-half)
    scan_fused<<<dim3((NB * D_INNER) / 256), blk, 0, stream>>>(
        xc, dtb, dtbc, A_log, D_skip, xz);

    // 6.5) W_out split (dtb region now dead)
    split2<<<dim3((D_MODEL * D_INNER + 255) / 256), blk, 0, stream>>>(W_out, Wo3, D_MODEL, D_INNER);

    // 7) out = y @ W_out^T via MFMA (virtual K' = 3*1536)
    gemm_mfma_nt<<<dim3(D_MODEL / 128, MROWS / 128), blk, 0, stream>>>(
        y3, 4 * D_INNER, Wo3, 2 * D_INNER, out, D_MODEL, D_INNER);
}

// Round 5
// 668.620 us; speedup vs baseline: 2.7221x; 1.5171x over previous
//
#include <hip/hip_runtime.h>
#include <cmath>

#define D_MODEL 768
#define D_STATE 8
#define D_CONV  4
#define D_INNER 1536
#define DT_RANK 48
#define NB 8
#define NS 1024
#define MROWS (NB*NS)   // 8192

#define I_TILE 64
#define NCH    8            // time chunks
#define CLEN   (NS/NCH)     // 128 steps per chunk

typedef short s16x8 __attribute__((ext_vector_type(8)));
typedef float f32x4 __attribute__((ext_vector_type(4)));

__device__ __forceinline__ float sigmoidf_(float x) { return 1.f / (1.f + __expf(-x)); }
__device__ __forceinline__ float softplusf_(float x) {
    return log1pf(__expf(-fabsf(x))) + fmaxf(x, 0.f);
}
__device__ __forceinline__ unsigned short f2bf(float v) {   // RNE float->bf16
    unsigned u = __float_as_uint(v);
    u += 0x7FFFu + ((u >> 16) & 1u);
    return (unsigned short)(u >> 16);
}
__device__ __forceinline__ float bf2f(unsigned short s) {
    return __uint_as_float(((unsigned)s) << 16);
}

// ---------------- split-bf16 [hi | lo] conversion (2K shorts per row) ----------------
__global__ __launch_bounds__(256) void split2(const float* __restrict__ src,
                                              unsigned short* __restrict__ dst,
                                              int rows, int K)
{
    int idx = blockIdx.x * 256 + threadIdx.x;
    if (idx >= rows * K) return;
    int r = idx / K, k = idx - r * K;
    float v = src[idx];
    unsigned short h  = f2bf(v);
    unsigned short lo = f2bf(v - bf2f(h));
    unsigned short* d = dst + (size_t)r * 2 * K + k;
    d[0] = h;
    d[K] = lo;
}

// ---------------- MFMA GEMM: C[M,N] = A*B^T in 3-term split-bf16 ----------------
// A stored [hi|lo] (2K shorts, row stride lda); virtual K' = 3K with
// A channels [hi|lo|hi]  -> kA = k0<2K ? k0 : k0-2K
// B channels [hi|hi|lo]  -> kB = k0<K  ? k0 : k0-K
// Register-staged LDS (compiler-ordered vs __syncthreads — no replay race).
__global__ __launch_bounds__(256) void gemm_mfma_nt(const unsigned short* __restrict__ A,
                                                    int lda,
                                                    const unsigned short* __restrict__ B,
                                                    int ldb,
                                                    float* __restrict__ C,
                                                    int ldc, int K)
{
    __shared__ unsigned short Ash[128][40];   // 10 KB
    __shared__ unsigned short Bsh[128][40];   // 10 KB
    const int tid = threadIdx.x;
    const int w  = tid >> 6;            // wave 0..3
    const int l  = tid & 63;
    const int wr = w >> 1, wc = w & 1;  // wave -> 64x64 quadrant
    const int lr = l & 15, lg = l >> 4;
    const long bm = (long)blockIdx.y * 128;
    const long bn = (long)blockIdx.x * 128;

    const int srow  = tid >> 1;
    const int shalf = tid & 1;
    const unsigned short* gA = A + (size_t)(bm + srow) * lda + shalf * 16;
    const unsigned short* gB = B + (size_t)(bn + srow) * ldb + shalf * 16;
    unsigned short* lA = &Ash[srow][shalf * 16];
    unsigned short* lB = &Bsh[srow][shalf * 16];

    f32x4 acc[4][4] = {};

    const int K3 = 3 * K;
    for (int k0 = 0; k0 < K3; k0 += 32) {
        const int kA = (k0 < 2 * K) ? k0 : k0 - 2 * K;
        const int kB = (k0 < K) ? k0 : k0 - K;
        s16x8 ra0 = *(const s16x8*)(gA + kA);
        s16x8 ra1 = *(const s16x8*)(gA + kA + 8);
        s16x8 rb0 = *(const s16x8*)(gB + kB);
        s16x8 rb1 = *(const s16x8*)(gB + kB + 8);
        __syncthreads();
        *(s16x8*)(lA)     = ra0;
        *(s16x8*)(lA + 8) = ra1;
        *(s16x8*)(lB)     = rb0;
        *(s16x8*)(lB + 8) = rb1;
        __syncthreads();
        s16x8 af[4], bfr[4];
        #pragma unroll
        for (int m = 0; m < 4; ++m) {
            const int arow = wr * 64 + m * 16 + lr;
            const int brow = wc * 64 + m * 16 + lr;
            af[m]  = *(const s16x8*)(&Ash[arow][lg * 8]);
            bfr[m] = *(const s16x8*)(&Bsh[brow][lg * 8]);
        }
        #pragma unroll
        for (int m = 0; m < 4; ++m)
            #pragma unroll
            for (int n = 0; n < 4; ++n)
                acc[m][n] = __builtin_amdgcn_mfma_f32_16x16x32_bf16(af[m], bfr[n], acc[m][n], 0, 0, 0);
    }

    #pragma unroll
    for (int m = 0; m < 4; ++m) {
        #pragma unroll
        for (int n = 0; n < 4; ++n) {
            const size_t row0 = bm + wr * 64 + m * 16 + lg * 4;
            const int    col  = bn + wc * 64 + n * 16 + lr;
            #pragma unroll
            for (int r = 0; r < 4; ++r)
                C[(row0 + r) * (size_t)ldc + col] = acc[m][n][r];
        }
    }
}

// ---------------- fp32 vector GEMM (two small GEMMs) ----------------
template<int EPI>
__global__ __launch_bounds__(256) void gemm_nt(const float* __restrict__ A,
                                               const float* __restrict__ B,
                                               const float* __restrict__ bias,
                                               float* __restrict__ C,
                                               int M, int N, int K,
                                               int lda, int ldb, int ldc)
{
    __shared__ float As[16][65];
    __shared__ float Bs[16][65];
    const int bm = blockIdx.y * 64;
    const int bn = blockIdx.x * 64;
    const int tid = threadIdx.x;
    const int r  = tid >> 2;
    const int kk = (tid & 3) << 2;
    const int tr = tid >> 4;
    const int tc = tid & 15;

    float acc[4][4] = {};

    for (int k0 = 0; k0 < K; k0 += 16) {
        float4 av = *(const float4*)(A + (size_t)(bm + r) * lda + k0 + kk);
        float4 bv = *(const float4*)(B + (size_t)(bn + r) * ldb + k0 + kk);
        As[kk + 0][r] = av.x; As[kk + 1][r] = av.y; As[kk + 2][r] = av.z; As[kk + 3][r] = av.w;
        Bs[kk + 0][r] = bv.x; Bs[kk + 1][r] = bv.y; Bs[kk + 2][r] = bv.z; Bs[kk + 3][r] = bv.w;
        __syncthreads();
        #pragma unroll
        for (int k = 0; k < 16; ++k) {
            float a0 = As[k][tr * 4 + 0], a1 = As[k][tr * 4 + 1];
            float a2 = As[k][tr * 4 + 2], a3 = As[k][tr * 4 + 3];
            float b0 = Bs[k][tc * 4 + 0], b1 = Bs[k][tc * 4 + 1];
            float b2 = Bs[k][tc * 4 + 2], b3 = Bs[k][tc * 4 + 3];
            acc[0][0] += a0 * b0; acc[0][1] += a0 * b1; acc[0][2] += a0 * b2; acc[0][3] += a0 * b3;
            acc[1][0] += a1 * b0; acc[1][1] += a1 * b1; acc[1][2] += a1 * b2; acc[1][3] += a1 * b3;
            acc[2][0] += a2 * b0; acc[2][1] += a2 * b1; acc[2][2] += a2 * b2; acc[2][3] += a2 * b3;
            acc[3][0] += a3 * b0; acc[3][1] += a3 * b1; acc[3][2] += a3 * b2; acc[3][3] += a3 * b3;
        }
        __syncthreads();
    }

    #pragma unroll
    for (int i = 0; i < 4; ++i) {
        const int row = bm + tr * 4 + i;
        const int col = bn + tc * 4;
        float vv[4];
        #pragma unroll
        for (int j = 0; j < 4; ++j) {
            float t = acc[i][j];
            if (EPI == 1) t = softplusf_(t + bias[col + j]) + 1e-4f;
            vv[j] = t;
        }
        float4 v; v.x = vv[0]; v.y = vv[1]; v.z = vv[2]; v.w = vv[3];
        *(float4*)(C + (size_t)row * ldc + col) = v;
    }
}

// ---------------- depthwise causal conv + SiLU ----------------
__global__ __launch_bounds__(256) void conv_silu(const float* __restrict__ xz,
                                                 const float* __restrict__ cw,
                                                 const float* __restrict__ cb,
                                                 float* __restrict__ xc)
{
    const int idx = blockIdx.x * 256 + threadIdx.x;
    const int i  = idx % D_INNER;
    const int bs = idx / D_INNER;
    const int s  = bs & (NS - 1);
    float acc = cb[i];
    #pragma unroll
    for (int k = 0; k < 4; ++k) {
        const int sp = s - 3 + k;
        if (sp >= 0)
            acc += xz[(size_t)(bs - 3 + k) * (2 * D_INNER) + i] * cw[i * 4 + k];
    }
    xc[(size_t)bs * D_INNER + i] = acc * sigmoidf_(acc);
}

__global__ __launch_bounds__(256) void tanh_bc(float* __restrict__ dtbc)
{
    const int idx = blockIdx.x * 256 + threadIdx.x;
    const int row = idx >> 4;
    const int c   = idx & 15;
    float* p = dtbc + (size_t)row * 64 + DT_RANK + c;
    *p = tanhf(*p);
}

// ---------------- chunk-parallel selective scan ----------------
// Linear recurrence st = da*st + u is associative: chunk transform (A,S),
// compose (A1,S1)∘(A2,S2) = (A1*A2, A2*S1 + S2).
// Block = 512 thr = 8 waves x 64 lanes; wave w = time-chunk w (128 steps),
// lane = i-offset within a 64-wide i-tile (coalesced loads).
// Phase1: per-chunk (A,S) from zero state -> LDS.
// Phase2: 64i x 8n threads do 8-long serial prefix over chunks (in-place st0).
// Phase3: replay chunk from st0, fused y*silu(z) epilogue, bf16 hi|lo write.
__global__ __launch_bounds__(512) void scan_par(const float* __restrict__ xc,
                                                const float* __restrict__ dt,
                                                const float* __restrict__ dtbc,
                                                const float* __restrict__ A_log,
                                                const float* __restrict__ D_skip,
                                                float* xz)
{
    __shared__ float shA[NCH][8][I_TILE];   // 16 KB
    __shared__ float shS[NCH][8][I_TILE];   // 16 KB (becomes st0 in phase 2)

    const int tiles = D_INNER / I_TILE;              // 24
    const int b  = blockIdx.x / tiles;
    const int i0 = (blockIdx.x % tiles) * I_TILE;
    const int w  = threadIdx.x >> 6;                 // chunk 0..7
    const int l  = threadIdx.x & 63;                 // i offset
    const int i  = i0 + l;

    float a[8];
    #pragma unroll
    for (int n = 0; n < 8; ++n) a[n] = -__expf(A_log[i * 8 + n]);

    const size_t rb = (size_t)b * NS + (size_t)w * CLEN;

    // ---- phase 1: local chunk scan from zero state ----
    float Ap[8], S[8];
    #pragma unroll
    for (int n = 0; n < 8; ++n) { Ap[n] = 1.f; S[n] = 0.f; }
    for (int s = 0; s < CLEN; ++s) {
        const size_t row = rb + s;
        const float xv  = xc[row * D_INNER + i];
        const float dtv = dt[row * D_INNER + i];
        const float* bc = dtbc + row * 64 + DT_RANK;
        #pragma unroll
        for (int n = 0; n < 8; ++n) {
            const float da = __expf(dtv * a[n]);
            S[n]  = da * S[n] + (1.f - da) * bc[n] * xv;
            Ap[n] *= da;
        }
    }
    #pragma unroll
    for (int n = 0; n < 8; ++n) { shA[w][n][l] = Ap[n]; shS[w][n][l] = S[n]; }
    __syncthreads();

    // ---- phase 2: prefix over chunks; thread = (state n = w, lane l) ----
    {
        const int n2 = w;
        float run = 0.f;
        #pragma unroll
        for (int c = 0; c < NCH; ++c) {
            const float Ac = shA[c][n2][l];
            const float Sc = shS[c][n2][l];
            shS[c][n2][l] = run;               // exclusive start state for chunk c
            run = Sc + Ac * run;
        }
    }
    __syncthreads();

    // ---- phase 3: replay with correct start state + epilogue ----
    float st[8];
    #pragma unroll
    for (int n = 0; n < 8; ++n) st[n] = shS[w][n][l];
    const float dsk = D_skip[i];
    unsigned short* y3 = (unsigned short*)xz;
    for (int s = 0; s < CLEN; ++s) {
        const size_t row = rb + s;
        const float xv  = xc[row * D_INNER + i];
        const float dtv = dt[row * D_INNER + i];
        const float* bc = dtbc + row * 64 + DT_RANK;
        float accy = 0.f;
        #pragma unroll
        for (int n = 0; n < 8; ++n) {
            const float da = __expf(dtv * a[n]);
            st[n] = da * st[n] + (1.f - da) * bc[n] * xv;
            accy += st[n] * bc[8 + n];
        }
        const float y  = accy + dsk * xv;
        const float zv = xz[row * (2 * D_INNER) + D_INNER + i];
        const float ym = y * (zv * sigmoidf_(zv));
        unsigned short h  = f2bf(ym);
        unsigned short lo = f2bf(ym - bf2f(h));
        unsigned short* d = y3 + row * (size_t)(4 * D_INNER) + i;
        d[0]       = h;
        d[D_INNER] = lo;
    }
}

extern "C" void kernel_launch(void* const* d_in, const int* in_sizes, int n_in,
                              void* d_out, int out_size, void* d_ws, size_t ws_size,
                              hipStream_t stream) {
    const float* x      = (const float*)d_in[0];
    const float* W_in   = (const float*)d_in[1];
    const float* conv_w = (const float*)d_in[2];
    const float* conv_b = (const float*)d_in[3];
    const float* W_x    = (const float*)d_in[4];
    const float* W_dt   = (const float*)d_in[5];
    const float* b_dt   = (const float*)d_in[6];
    const float* A_log  = (const float*)d_in[7];
    const float* D_skip = (const float*)d_in[8];
    const float* W_out  = (const float*)d_in[9];
    float* out = (float*)d_out;

    // Workspace: EXACTLY the round-1 footprint (203,423,744 B, proven <= ws_size).
    char* wsb = (char*)d_ws;
    float* xz   = (float*)(wsb);                    // [8192][3072] f32 (y3 bf16 reuses x-half)
    float* xc   = (float*)(wsb + 100663296);        // [8192][1536] f32
    float* dtbc = (float*)(wsb + 150994944);        // [8192][64]   f32
    float* dtb  = (float*)(wsb + 153092096);        // [8192][1536] f32  (aliased below)
    unsigned short* x3  = (unsigned short*)(wsb + 153092096);  // dead before dtb
    unsigned short* W3  = (unsigned short*)(wsb + 178257920);  // dead before dtb
    unsigned short* Wo3 = (unsigned short*)(wsb + 153092096);  // born after dtb dies
    unsigned short* y3  = (unsigned short*)xz;                 // rows @ stride 6144 shorts

    dim3 blk(256);

    // 0) split-bf16 conversions for GEMM1
    split2<<<dim3((MROWS * D_MODEL + 255) / 256), blk, 0, stream>>>(x, x3, MROWS, D_MODEL);
    split2<<<dim3((2 * D_INNER * D_MODEL + 255) / 256), blk, 0, stream>>>(W_in, W3, 2 * D_INNER, D_MODEL);

    // 1) xz = x @ W_in^T via MFMA (virtual K' = 3*768)
    gemm_mfma_nt<<<dim3(3072 / 128, MROWS / 128), blk, 0, stream>>>(
        x3, 2 * D_MODEL, W3, 2 * D_MODEL, xz, 3072, D_MODEL);

    // 2) depthwise conv + silu -> xc
    conv_silu<<<dim3((MROWS * D_INNER) / 256), blk, 0, stream>>>(xz, conv_w, conv_b, xc);

    // 3) dtbc = xc @ W_x^T  (N=64, K=1536) — fp32 vector
    gemm_nt<0><<<dim3(64 / 64, MROWS / 64), blk, 0, stream>>>(
        xc, W_x, nullptr, dtbc, MROWS, 64, D_INNER, D_INNER, D_INNER, 64);

    // 4) tanh on b/c columns
    tanh_bc<<<dim3((MROWS * 16) / 256), blk, 0, stream>>>(dtbc);

    // 5) dt = softplus(dt_part @ W_dt^T + b_dt) + 1e-4 — fp32 vector
    gemm_nt<1><<<dim3(D_INNER / 64, MROWS / 64), blk, 0, stream>>>(
        dtbc, W_dt, b_dt, dtb, MROWS, D_INNER, DT_RANK, 64, DT_RANK, D_INNER);

    // 6) chunk-parallel scan + mix epilogue -> y3 (bf16 hi|lo over xz x-half)
    scan_par<<<dim3(NB * (D_INNER / I_TILE)), dim3(512), 0, stream>>>(
        xc, dtb, dtbc, A_log, D_skip, xz);

    // 6.5) W_out split (dtb region now dead)
    split2<<<dim3((D_MODEL * D_INNER + 255) / 256), blk, 0, stream>>>(W_out, Wo3, D_MODEL, D_INNER);

    // 7) out = y @ W_out^T via MFMA (virtual K' = 3*1536)
    gemm_mfma_nt<<<dim3(D_MODEL / 128, MROWS / 128), blk, 0, stream>>>(
        y3, 4 * D_INNER, Wo3, 2 * D_INNER, out, D_MODEL, D_INNER);
}

// Round 6
// 612.077 us; speedup vs baseline: 2.9735x; 1.0924x over previous
//
#include <hip/hip_runtime.h>
#include <cmath>

#define D_MODEL 768
#define D_STATE 8
#define D_CONV  4
#define D_INNER 1536
#define DT_RANK 48
#define NB 8
#define NS 1024
#define MROWS (NB*NS)   // 8192

#define I_TILE 64
#define NCH    8            // time chunks
#define CLEN   (NS/NCH)     // 128 steps per chunk

typedef short s16x8 __attribute__((ext_vector_type(8)));
typedef float f32x4 __attribute__((ext_vector_type(4)));

__device__ __forceinline__ float sigmoidf_(float x) { return 1.f / (1.f + __expf(-x)); }
__device__ __forceinline__ float softplusf_(float x) {
    return log1pf(__expf(-fabsf(x))) + fmaxf(x, 0.f);
}
__device__ __forceinline__ unsigned short f2bf(float v) {   // RNE float->bf16
    unsigned u = __float_as_uint(v);
    u += 0x7FFFu + ((u >> 16) & 1u);
    return (unsigned short)(u >> 16);
}
__device__ __forceinline__ float bf2f(unsigned short s) {
    return __uint_as_float(((unsigned)s) << 16);
}
__device__ __forceinline__ void gload16(const void* g, void* l) {
    __builtin_amdgcn_global_load_lds(
        (__attribute__((address_space(1))) void*)(unsigned long long)g,
        (__attribute__((address_space(3))) void*)l, 16, 0, 0);
}

// ---------------- split-bf16 [hi | lo] conversion (2K shorts per row) ----------------
__global__ __launch_bounds__(256) void split2(const float* __restrict__ src,
                                              unsigned short* __restrict__ dst,
                                              int rows, int K)
{
    int idx = blockIdx.x * 256 + threadIdx.x;
    if (idx >= rows * K) return;
    int r = idx / K, k = idx - r * K;
    float v = src[idx];
    unsigned short h  = f2bf(v);
    unsigned short lo = f2bf(v - bf2f(h));
    unsigned short* d = dst + (size_t)r * 2 * K + k;
    d[0] = h;
    d[K] = lo;
}

// ---------------- MFMA GEMM: C[M,N] = A*B^T in 3-term split-bf16 ----------------
// A stored [hi|lo] (2K shorts); virtual K' = 3K: A channels [hi|lo|hi], B [hi|hi|lo].
// 128x128 tile, BK=32, 4 waves. global_load_lds + DOUBLE-BUFFERED LDS:
// stage(t+1) writes buf^1 while frags read buf -> one barrier per K-step.
// sched_barrier(0) fences both sides of each __syncthreads pin the un-modeled
// LDS-write of global_load_lds inside its iteration (round-3 race fix).
// Chunk swizzle: LDS linear dest; global source column pre-swizzled by
// ((row&3)<<4) byte-XOR; ds_read applies the same involution.
__global__ __launch_bounds__(256) void gemm_mfma_nt(const unsigned short* __restrict__ A,
                                                    int lda,
                                                    const unsigned short* __restrict__ B,
                                                    int ldb,
                                                    float* __restrict__ C,
                                                    int ldc, int K)
{
    __shared__ unsigned short Ash[2][128 * 32];   // 2 x 8 KB
    __shared__ unsigned short Bsh[2][128 * 32];   // 2 x 8 KB
    const int tid = threadIdx.x;
    const int w  = tid >> 6;            // wave 0..3
    const int l  = tid & 63;
    const int wr = w >> 1, wc = w & 1;  // wave -> 64x64 quadrant
    const int lr = l & 15, lg = l >> 4;

    // bijective XCD swizzle (nwg % 8 == 0 for both call sites)
    const int gx = gridDim.x;
    const int nwg = gx * gridDim.y;
    const int id  = blockIdx.y * gx + blockIdx.x;
    const int swz = (id & 7) * (nwg >> 3) + (id >> 3);
    const long bm = (long)(swz / gx) * 128;
    const long bn = (long)(swz % gx) * 128;

    // staging geometry: tile = 128 rows x 64 B; wave w stages bytes [w*2048, w*2048+2048)
    const int p0 = w * 2048 + l * 16;
    const int p1 = p0 + 1024;
    const int r0 = p0 >> 6, c0 = (p0 & 63) ^ ((r0 & 3) << 4);  // pre-swizzled src col (bytes)
    const int r1 = p1 >> 6, c1 = (p1 & 63) ^ ((r1 & 3) << 4);

    const unsigned short* rA0 = A + (size_t)(bm + r0) * lda + (c0 >> 1);
    const unsigned short* rA1 = A + (size_t)(bm + r1) * lda + (c1 >> 1);
    const unsigned short* rB0 = B + (size_t)(bn + r0) * ldb + (c0 >> 1);
    const unsigned short* rB1 = B + (size_t)(bn + r1) * ldb + (c1 >> 1);

    // fragment ds_read byte offsets (swizzled); arow&3 == lr&3
    int aoff[4], boff[4];
    #pragma unroll
    for (int m = 0; m < 4; ++m) {
        int arow = wr * 64 + m * 16 + lr;
        int brow = wc * 64 + m * 16 + lr;
        aoff[m] = (arow * 64 + lg * 16) ^ ((lr & 3) << 4);
        boff[m] = (brow * 64 + lg * 16) ^ ((lr & 3) << 4);
    }

    const int K3 = 3 * K;
    const int T  = K3 / 32;

    // stage K-step t into LDS buffer `buf` (wave-uniform dest + lane*16, HW rule)
    auto stage = [&](int buf, int t) {
        const int k0 = t * 32;
        const int kA = (k0 < 2 * K) ? k0 : k0 - 2 * K;
        const int kB = (k0 < K) ? k0 : k0 - K;
        unsigned short* a0 = &Ash[buf][w * 1024];
        unsigned short* b0 = &Bsh[buf][w * 1024];
        gload16(rA0 + kA, a0);
        gload16(rA1 + kA, a0 + 512);
        gload16(rB0 + kB, b0);
        gload16(rB1 + kB, b0 + 512);
    };

    f32x4 acc[4][4] = {};

    stage(0, 0);
    __builtin_amdgcn_sched_barrier(0);
    __syncthreads();                         // vmcnt(0) drained by compiler
    __builtin_amdgcn_sched_barrier(0);

    int cur = 0;
    for (int t = 0; t < T; ++t) {
        if (t + 1 < T) stage(cur ^ 1, t + 1);        // writes other buffer
        s16x8 af[4], bfr[4];
        #pragma unroll
        for (int m = 0; m < 4; ++m) {
            af[m]  = *(const s16x8*)((const char*)&Ash[cur][0] + aoff[m]);
            bfr[m] = *(const s16x8*)((const char*)&Bsh[cur][0] + boff[m]);
        }
        #pragma unroll
        for (int m = 0; m < 4; ++m)
            #pragma unroll
            for (int n = 0; n < 4; ++n)
                acc[m][n] = __builtin_amdgcn_mfma_f32_16x16x32_bf16(af[m], bfr[n], acc[m][n], 0, 0, 0);
        __builtin_amdgcn_sched_barrier(0);
        __syncthreads();                     // drains vmcnt -> next buf ready; readers done
        __builtin_amdgcn_sched_barrier(0);
        cur ^= 1;
    }

    // C/D layout: col = lane&15, row = (lane>>4)*4 + reg
    #pragma unroll
    for (int m = 0; m < 4; ++m) {
        #pragma unroll
        for (int n = 0; n < 4; ++n) {
            const size_t row0 = bm + wr * 64 + m * 16 + lg * 4;
            const int    col  = bn + wc * 64 + n * 16 + lr;
            #pragma unroll
            for (int r = 0; r < 4; ++r)
                C[(row0 + r) * (size_t)ldc + col] = acc[m][n][r];
        }
    }
}

// ---------------- fp32 vector GEMM (two small GEMMs) ----------------
// EPI 0: plain. EPI 1: softplus(acc+bias)+1e-4. EPI 2: tanh on cols >= DT_RANK.
template<int EPI>
__global__ __launch_bounds__(256) void gemm_nt(const float* __restrict__ A,
                                               const float* __restrict__ B,
                                               const float* __restrict__ bias,
                                               float* __restrict__ C,
                                               int M, int N, int K,
                                               int lda, int ldb, int ldc)
{
    __shared__ float As[16][65];
    __shared__ float Bs[16][65];
    const int bm = blockIdx.y * 64;
    const int bn = blockIdx.x * 64;
    const int tid = threadIdx.x;
    const int r  = tid >> 2;
    const int kk = (tid & 3) << 2;
    const int tr = tid >> 4;
    const int tc = tid & 15;

    float acc[4][4] = {};

    for (int k0 = 0; k0 < K; k0 += 16) {
        float4 av = *(const float4*)(A + (size_t)(bm + r) * lda + k0 + kk);
        float4 bv = *(const float4*)(B + (size_t)(bn + r) * ldb + k0 + kk);
        As[kk + 0][r] = av.x; As[kk + 1][r] = av.y; As[kk + 2][r] = av.z; As[kk + 3][r] = av.w;
        Bs[kk + 0][r] = bv.x; Bs[kk + 1][r] = bv.y; Bs[kk + 2][r] = bv.z; Bs[kk + 3][r] = bv.w;
        __syncthreads();
        #pragma unroll
        for (int k = 0; k < 16; ++k) {
            float a0 = As[k][tr * 4 + 0], a1 = As[k][tr * 4 + 1];
            float a2 = As[k][tr * 4 + 2], a3 = As[k][tr * 4 + 3];
            float b0 = Bs[k][tc * 4 + 0], b1 = Bs[k][tc * 4 + 1];
            float b2 = Bs[k][tc * 4 + 2], b3 = Bs[k][tc * 4 + 3];
            acc[0][0] += a0 * b0; acc[0][1] += a0 * b1; acc[0][2] += a0 * b2; acc[0][3] += a0 * b3;
            acc[1][0] += a1 * b0; acc[1][1] += a1 * b1; acc[1][2] += a1 * b2; acc[1][3] += a1 * b3;
            acc[2][0] += a2 * b0; acc[2][1] += a2 * b1; acc[2][2] += a2 * b2; acc[2][3] += a2 * b3;
            acc[3][0] += a3 * b0; acc[3][1] += a3 * b1; acc[3][2] += a3 * b2; acc[3][3] += a3 * b3;
        }
        __syncthreads();
    }

    #pragma unroll
    for (int i = 0; i < 4; ++i) {
        const int row = bm + tr * 4 + i;
        const int col = bn + tc * 4;
        float vv[4];
        #pragma unroll
        for (int j = 0; j < 4; ++j) {
            float t = acc[i][j];
            if (EPI == 1) t = softplusf_(t + bias[col + j]) + 1e-4f;
            if (EPI == 2 && (col + j) >= DT_RANK) t = tanhf(t);
            vv[j] = t;
        }
        float4 v; v.x = vv[0]; v.y = vv[1]; v.z = vv[2]; v.w = vv[3];
        *(float4*)(C + (size_t)row * ldc + col) = v;
    }
}

// ---------------- depthwise causal conv + SiLU ----------------
__global__ __launch_bounds__(256) void conv_silu(const float* __restrict__ xz,
                                                 const float* __restrict__ cw,
                                                 const float* __restrict__ cb,
                                                 float* __restrict__ xc)
{
    const int idx = blockIdx.x * 256 + threadIdx.x;
    const int i  = idx % D_INNER;
    const int bs = idx / D_INNER;
    const int s  = bs & (NS - 1);
    float acc = cb[i];
    #pragma unroll
    for (int k = 0; k < 4; ++k) {
        const int sp = s - 3 + k;
        if (sp >= 0)
            acc += xz[(size_t)(bs - 3 + k) * (2 * D_INNER) + i] * cw[i * 4 + k];
    }
    xc[(size_t)bs * D_INNER + i] = acc * sigmoidf_(acc);
}

// ---------------- chunk-parallel selective scan ----------------
__global__ __launch_bounds__(512) void scan_par(const float* __restrict__ xc,
                                                const float* __restrict__ dt,
                                                const float* __restrict__ dtbc,
                                                const float* __restrict__ A_log,
                                                const float* __restrict__ D_skip,
                                                float* xz)
{
    __shared__ float shA[NCH][8][I_TILE];   // 16 KB
    __shared__ float shS[NCH][8][I_TILE];   // 16 KB (becomes st0 in phase 2)

    const int tiles = D_INNER / I_TILE;              // 24
    const int b  = blockIdx.x / tiles;
    const int i0 = (blockIdx.x % tiles) * I_TILE;
    const int w  = threadIdx.x >> 6;                 // chunk 0..7
    const int l  = threadIdx.x & 63;                 // i offset
    const int i  = i0 + l;

    float a[8];
    #pragma unroll
    for (int n = 0; n < 8; ++n) a[n] = -__expf(A_log[i * 8 + n]);

    const size_t rb = (size_t)b * NS + (size_t)w * CLEN;

    // ---- phase 1: local chunk scan from zero state ----
    float Ap[8], S[8];
    #pragma unroll
    for (int n = 0; n < 8; ++n) { Ap[n] = 1.f; S[n] = 0.f; }
    for (int s = 0; s < CLEN; ++s) {
        const size_t row = rb + s;
        const float xv  = xc[row * D_INNER + i];
        const float dtv = dt[row * D_INNER + i];
        const float* bc = dtbc + row * 64 + DT_RANK;
        #pragma unroll
        for (int n = 0; n < 8; ++n) {
            const float da = __expf(dtv * a[n]);
            S[n]  = da * S[n] + (1.f - da) * bc[n] * xv;
            Ap[n] *= da;
        }
    }
    #pragma unroll
    for (int n = 0; n < 8; ++n) { shA[w][n][l] = Ap[n]; shS[w][n][l] = S[n]; }
    __syncthreads();

    // ---- phase 2: prefix over chunks; thread = (state n = w, lane l) ----
    {
        const int n2 = w;
        float run = 0.f;
        #pragma unroll
        for (int c = 0; c < NCH; ++c) {
            const float Ac = shA[c][n2][l];
            const float Sc = shS[c][n2][l];
            shS[c][n2][l] = run;               // exclusive start state for chunk c
            run = Sc + Ac * run;
        }
    }
    __syncthreads();

    // ---- phase 3: replay with correct start state + epilogue ----
    float st[8];
    #pragma unroll
    for (int n = 0; n < 8; ++n) st[n] = shS[w][n][l];
    const float dsk = D_skip[i];
    unsigned short* y3 = (unsigned short*)xz;
    for (int s = 0; s < CLEN; ++s) {
        const size_t row = rb + s;
        const float xv  = xc[row * D_INNER + i];
        const float dtv = dt[row * D_INNER + i];
        const float* bc = dtbc + row * 64 + DT_RANK;
        float accy = 0.f;
        #pragma unroll
        for (int n = 0; n < 8; ++n) {
            const float da = __expf(dtv * a[n]);
            st[n] = da * st[n] + (1.f - da) * bc[n] * xv;
            accy += st[n] * bc[8 + n];
        }
        const float y  = accy + dsk * xv;
        const float zv = xz[row * (2 * D_INNER) + D_INNER + i];
        const float ym = y * (zv * sigmoidf_(zv));
        unsigned short h  = f2bf(ym);
        unsigned short lo = f2bf(ym - bf2f(h));
        unsigned short* d = y3 + row * (size_t)(4 * D_INNER) + i;
        d[0]       = h;
        d[D_INNER] = lo;
    }
}

extern "C" void kernel_launch(void* const* d_in, const int* in_sizes, int n_in,
                              void* d_out, int out_size, void* d_ws, size_t ws_size,
                              hipStream_t stream) {
    const float* x      = (const float*)d_in[0];
    const float* W_in   = (const float*)d_in[1];
    const float* conv_w = (const float*)d_in[2];
    const float* conv_b = (const float*)d_in[3];
    const float* W_x    = (const float*)d_in[4];
    const float* W_dt   = (const float*)d_in[5];
    const float* b_dt   = (const float*)d_in[6];
    const float* A_log  = (const float*)d_in[7];
    const float* D_skip = (const float*)d_in[8];
    const float* W_out  = (const float*)d_in[9];
    float* out = (float*)d_out;

    // Workspace: EXACTLY the round-1 footprint (203,423,744 B, proven <= ws_size).
    char* wsb = (char*)d_ws;
    float* xz   = (float*)(wsb);                    // [8192][3072] f32 (y3 bf16 reuses x-half)
    float* xc   = (float*)(wsb + 100663296);        // [8192][1536] f32
    float* dtbc = (float*)(wsb + 150994944);        // [8192][64]   f32
    float* dtb  = (float*)(wsb + 153092096);        // [8192][1536] f32  (aliased below)
    unsigned short* x3  = (unsigned short*)(wsb + 153092096);  // dead before dtb
    unsigned short* W3  = (unsigned short*)(wsb + 178257920);  // dead before dtb
    unsigned short* Wo3 = (unsigned short*)(wsb + 153092096);  // born after dtb dies
    unsigned short* y3  = (unsigned short*)xz;                 // rows @ stride 6144 shorts

    dim3 blk(256);

    // 0) split-bf16 conversions for GEMM1
    split2<<<dim3((MROWS * D_MODEL + 255) / 256), blk, 0, stream>>>(x, x3, MROWS, D_MODEL);
    split2<<<dim3((2 * D_INNER * D_MODEL + 255) / 256), blk, 0, stream>>>(W_in, W3, 2 * D_INNER, D_MODEL);

    // 1) xz = x @ W_in^T via MFMA (virtual K' = 3*768)
    gemm_mfma_nt<<<dim3(3072 / 128, MROWS / 128), blk, 0, stream>>>(
        x3, 2 * D_MODEL, W3, 2 * D_MODEL, xz, 3072, D_MODEL);

    // 2) depthwise conv + silu -> xc
    conv_silu<<<dim3((MROWS * D_INNER) / 256), blk, 0, stream>>>(xz, conv_w, conv_b, xc);

    // 3) dtbc = xc @ W_x^T  (N=64, K=1536) with fused tanh on cols >= 48
    gemm_nt<2><<<dim3(64 / 64, MROWS / 64), blk, 0, stream>>>(
        xc, W_x, nullptr, dtbc, MROWS, 64, D_INNER, D_INNER, D_INNER, 64);

    // 5) dt = softplus(dt_part @ W_dt^T + b_dt) + 1e-4 — fp32 vector
    gemm_nt<1><<<dim3(D_INNER / 64, MROWS / 64), blk, 0, stream>>>(
        dtbc, W_dt, b_dt, dtb, MROWS, D_INNER, DT_RANK, 64, DT_RANK, D_INNER);

    // 6) chunk-parallel scan + mix epilogue -> y3 (bf16 hi|lo over xz x-half)
    scan_par<<<dim3(NB * (D_INNER / I_TILE)), dim3(512), 0, stream>>>(
        xc, dtb, dtbc, A_log, D_skip, xz);

    // 6.5) W_out split (dtb region now dead)
    split2<<<dim3((D_MODEL * D_INNER + 255) / 256), blk, 0, stream>>>(W_out, Wo3, D_MODEL, D_INNER);

    // 7) out = y @ W_out^T via MFMA (virtual K' = 3*1536)
    gemm_mfma_nt<<<dim3(D_MODEL / 128, MROWS / 128), blk, 0, stream>>>(
        y3, 4 * D_INNER, Wo3, 2 * D_INNER, out, D_MODEL, D_INNER);
}

// Round 7
// 541.754 us; speedup vs baseline: 3.3595x; 1.1298x over previous
//
#include <hip/hip_runtime.h>
#include <cmath>

#define D_MODEL 768
#define D_STATE 8
#define D_CONV  4
#define D_INNER 1536
#define DT_RANK 48
#define NB 8
#define NS 1024
#define MROWS (NB*NS)   // 8192

#define I_TILE 64
#define NCH    8            // time chunks
#define CLEN   (NS/NCH)     // 128 steps per chunk

typedef short s16x8 __attribute__((ext_vector_type(8)));
typedef float f32x4 __attribute__((ext_vector_type(4)));

__device__ __forceinline__ float sigmoidf_(float x) { return 1.f / (1.f + __expf(-x)); }
__device__ __forceinline__ float softplusf_(float x) {
    return log1pf(__expf(-fabsf(x))) + fmaxf(x, 0.f);
}
__device__ __forceinline__ unsigned short f2bf(float v) {   // RNE float->bf16
    unsigned u = __float_as_uint(v);
    u += 0x7FFFu + ((u >> 16) & 1u);
    return (unsigned short)(u >> 16);
}
__device__ __forceinline__ float bf2f(unsigned short s) {
    return __uint_as_float(((unsigned)s) << 16);
}
__device__ __forceinline__ void gload16(const void* g, void* l) {
    __builtin_amdgcn_global_load_lds(
        (__attribute__((address_space(1))) void*)(unsigned long long)g,
        (__attribute__((address_space(3))) void*)l, 16, 0, 0);
}

// ---------------- split-bf16 [hi | lo] conversion (A-side, 2K shorts per row) ----------------
__global__ __launch_bounds__(256) void split2(const float* __restrict__ src,
                                              unsigned short* __restrict__ dst,
                                              int rows, int K)
{
    int idx = blockIdx.x * 256 + threadIdx.x;
    if (idx >= rows * K) return;
    int r = idx / K, k = idx - r * K;
    float v = src[idx];
    unsigned short h  = f2bf(v);
    unsigned short lo = f2bf(v - bf2f(h));
    unsigned short* d = dst + (size_t)r * 2 * K + k;
    d[0] = h;
    d[K] = lo;
}

// ---------------- bf16 hi-only conversion (B-side) ----------------
__global__ __launch_bounds__(256) void split1(const float* __restrict__ src,
                                              unsigned short* __restrict__ dst,
                                              int n)
{
    int idx = blockIdx.x * 256 + threadIdx.x;
    if (idx >= n) return;
    dst[idx] = f2bf(src[idx]);
}

// ---------------- MFMA GEMM: C[M,N] = A*B^T in 2-term split-bf16 ----------------
// A stored [hi|lo] (2K shorts, row stride lda); B stored hi-only (K shorts, ldb).
// Virtual K' = 2K: computes a_hi*b_hi + a_lo*b_hi (error ~2^-9 relative).
//   kA = k0 (direct), kB = k0<K ? k0 : k0-K.
// 128x128 tile, BK=32, 4 waves. global_load_lds + DOUBLE-BUFFERED LDS:
// stage(t+1) writes buf^1 while frags read buf -> one barrier per K-step.
// sched_barrier(0) fences both sides of each __syncthreads pin the un-modeled
// LDS-write of global_load_lds inside its iteration (round-3 race fix).
// Chunk swizzle: LDS linear dest; global source column pre-swizzled by
// ((row&3)<<4) byte-XOR; ds_read applies the same involution.
__global__ __launch_bounds__(256) void gemm_mfma_nt(const unsigned short* __restrict__ A,
                                                    int lda,
                                                    const unsigned short* __restrict__ B,
                                                    int ldb,
                                                    float* __restrict__ C,
                                                    int ldc, int K)
{
    __shared__ unsigned short Ash[2][128 * 32];   // 2 x 8 KB
    __shared__ unsigned short Bsh[2][128 * 32];   // 2 x 8 KB
    const int tid = threadIdx.x;
    const int w  = tid >> 6;            // wave 0..3
    const int l  = tid & 63;
    const int wr = w >> 1, wc = w & 1;  // wave -> 64x64 quadrant
    const int lr = l & 15, lg = l >> 4;

    // bijective XCD swizzle (nwg % 8 == 0 for both call sites)
    const int gx = gridDim.x;
    const int nwg = gx * gridDim.y;
    const int id  = blockIdx.y * gx + blockIdx.x;
    const int swz = (id & 7) * (nwg >> 3) + (id >> 3);
    const long bm = (long)(swz / gx) * 128;
    const long bn = (long)(swz % gx) * 128;

    // staging geometry: tile = 128 rows x 64 B; wave w stages bytes [w*2048, w*2048+2048)
    const int p0 = w * 2048 + l * 16;
    const int p1 = p0 + 1024;
    const int r0 = p0 >> 6, c0 = (p0 & 63) ^ ((r0 & 3) << 4);  // pre-swizzled src col (bytes)
    const int r1 = p1 >> 6, c1 = (p1 & 63) ^ ((r1 & 3) << 4);

    const unsigned short* rA0 = A + (size_t)(bm + r0) * lda + (c0 >> 1);
    const unsigned short* rA1 = A + (size_t)(bm + r1) * lda + (c1 >> 1);
    const unsigned short* rB0 = B + (size_t)(bn + r0) * ldb + (c0 >> 1);
    const unsigned short* rB1 = B + (size_t)(bn + r1) * ldb + (c1 >> 1);

    // fragment ds_read byte offsets (swizzled); arow&3 == lr&3
    int aoff[4], boff[4];
    #pragma unroll
    for (int m = 0; m < 4; ++m) {
        int arow = wr * 64 + m * 16 + lr;
        int brow = wc * 64 + m * 16 + lr;
        aoff[m] = (arow * 64 + lg * 16) ^ ((lr & 3) << 4);
        boff[m] = (brow * 64 + lg * 16) ^ ((lr & 3) << 4);
    }

    const int K2 = 2 * K;
    const int T  = K2 / 32;

    // stage K-step t into LDS buffer `buf` (wave-uniform dest + lane*16, HW rule)
    auto stage = [&](int buf, int t) {
        const int k0 = t * 32;
        const int kB = (k0 < K) ? k0 : k0 - K;
        unsigned short* a0 = &Ash[buf][w * 1024];
        unsigned short* b0 = &Bsh[buf][w * 1024];
        gload16(rA0 + k0, a0);
        gload16(rA1 + k0, a0 + 512);
        gload16(rB0 + kB, b0);
        gload16(rB1 + kB, b0 + 512);
    };

    f32x4 acc[4][4] = {};

    stage(0, 0);
    __builtin_amdgcn_sched_barrier(0);
    __syncthreads();                         // vmcnt(0) drained by compiler
    __builtin_amdgcn_sched_barrier(0);

    int cur = 0;
    for (int t = 0; t < T; ++t) {
        if (t + 1 < T) stage(cur ^ 1, t + 1);        // writes other buffer
        s16x8 af[4], bfr[4];
        #pragma unroll
        for (int m = 0; m < 4; ++m) {
            af[m]  = *(const s16x8*)((const char*)&Ash[cur][0] + aoff[m]);
            bfr[m] = *(const s16x8*)((const char*)&Bsh[cur][0] + boff[m]);
        }
        #pragma unroll
        for (int m = 0; m < 4; ++m)
            #pragma unroll
            for (int n = 0; n < 4; ++n)
                acc[m][n] = __builtin_amdgcn_mfma_f32_16x16x32_bf16(af[m], bfr[n], acc[m][n], 0, 0, 0);
        __builtin_amdgcn_sched_barrier(0);
        __syncthreads();                     // drains vmcnt -> next buf ready; readers done
        __builtin_amdgcn_sched_barrier(0);
        cur ^= 1;
    }

    // C/D layout: col = lane&15, row = (lane>>4)*4 + reg
    #pragma unroll
    for (int m = 0; m < 4; ++m) {
        #pragma unroll
        for (int n = 0; n < 4; ++n) {
            const size_t row0 = bm + wr * 64 + m * 16 + lg * 4;
            const int    col  = bn + wc * 64 + n * 16 + lr;
            #pragma unroll
            for (int r = 0; r < 4; ++r)
                C[(row0 + r) * (size_t)ldc + col] = acc[m][n][r];
        }
    }
}

// ---------------- fp32 vector GEMM (two small GEMMs) ----------------
// EPI 0: plain. EPI 1: softplus(acc+bias)+1e-4. EPI 2: tanh on cols >= DT_RANK.
template<int EPI>
__global__ __launch_bounds__(256) void gemm_nt(const float* __restrict__ A,
                                               const float* __restrict__ B,
                                               const float* __restrict__ bias,
                                               float* __restrict__ C,
                                               int M, int N, int K,
                                               int lda, int ldb, int ldc)
{
    __shared__ float As[16][65];
    __shared__ float Bs[16][65];
    const int bm = blockIdx.y * 64;
    const int bn = blockIdx.x * 64;
    const int tid = threadIdx.x;
    const int r  = tid >> 2;
    const int kk = (tid & 3) << 2;
    const int tr = tid >> 4;
    const int tc = tid & 15;

    float acc[4][4] = {};

    for (int k0 = 0; k0 < K; k0 += 16) {
        float4 av = *(const float4*)(A + (size_t)(bm + r) * lda + k0 + kk);
        float4 bv = *(const float4*)(B + (size_t)(bn + r) * ldb + k0 + kk);
        As[kk + 0][r] = av.x; As[kk + 1][r] = av.y; As[kk + 2][r] = av.z; As[kk + 3][r] = av.w;
        Bs[kk + 0][r] = bv.x; Bs[kk + 1][r] = bv.y; Bs[kk + 2][r] = bv.z; Bs[kk + 3][r] = bv.w;
        __syncthreads();
        #pragma unroll
        for (int k = 0; k < 16; ++k) {
            float a0 = As[k][tr * 4 + 0], a1 = As[k][tr * 4 + 1];
            float a2 = As[k][tr * 4 + 2], a3 = As[k][tr * 4 + 3];
            float b0 = Bs[k][tc * 4 + 0], b1 = Bs[k][tc * 4 + 1];
            float b2 = Bs[k][tc * 4 + 2], b3 = Bs[k][tc * 4 + 3];
            acc[0][0] += a0 * b0; acc[0][1] += a0 * b1; acc[0][2] += a0 * b2; acc[0][3] += a0 * b3;
            acc[1][0] += a1 * b0; acc[1][1] += a1 * b1; acc[1][2] += a1 * b2; acc[1][3] += a1 * b3;
            acc[2][0] += a2 * b0; acc[2][1] += a2 * b1; acc[2][2] += a2 * b2; acc[2][3] += a2 * b3;
            acc[3][0] += a3 * b0; acc[3][1] += a3 * b1; acc[3][2] += a3 * b2; acc[3][3] += a3 * b3;
        }
        __syncthreads();
    }

    #pragma unroll
    for (int i = 0; i < 4; ++i) {
        const int row = bm + tr * 4 + i;
        const int col = bn + tc * 4;
        float vv[4];
        #pragma unroll
        for (int j = 0; j < 4; ++j) {
            float t = acc[i][j];
            if (EPI == 1) t = softplusf_(t + bias[col + j]) + 1e-4f;
            if (EPI == 2 && (col + j) >= DT_RANK) t = tanhf(t);
            vv[j] = t;
        }
        float4 v; v.x = vv[0]; v.y = vv[1]; v.z = vv[2]; v.w = vv[3];
        *(float4*)(C + (size_t)row * ldc + col) = v;
    }
}

// ---------------- depthwise causal conv + SiLU ----------------
__global__ __launch_bounds__(256) void conv_silu(const float* __restrict__ xz,
                                                 const float* __restrict__ cw,
                                                 const float* __restrict__ cb,
                                                 float* __restrict__ xc)
{
    const int idx = blockIdx.x * 256 + threadIdx.x;
    const int i  = idx % D_INNER;
    const int bs = idx / D_INNER;
    const int s  = bs & (NS - 1);
    float acc = cb[i];
    #pragma unroll
    for (int k = 0; k < 4; ++k) {
        const int sp = s - 3 + k;
        if (sp >= 0)
            acc += xz[(size_t)(bs - 3 + k) * (2 * D_INNER) + i] * cw[i * 4 + k];
    }
    xc[(size_t)bs * D_INNER + i] = acc * sigmoidf_(acc);
}

// ---------------- chunk-parallel selective scan ----------------
__global__ __launch_bounds__(512) void scan_par(const float* __restrict__ xc,
                                                const float* __restrict__ dt,
                                                const float* __restrict__ dtbc,
                                                const float* __restrict__ A_log,
                                                const float* __restrict__ D_skip,
                                                float* xz)
{
    __shared__ float shA[NCH][8][I_TILE];   // 16 KB
    __shared__ float shS[NCH][8][I_TILE];   // 16 KB (becomes st0 in phase 2)

    const int tiles = D_INNER / I_TILE;              // 24
    const int b  = blockIdx.x / tiles;
    const int i0 = (blockIdx.x % tiles) * I_TILE;
    const int w  = threadIdx.x >> 6;                 // chunk 0..7
    const int l  = threadIdx.x & 63;                 // i offset
    const int i  = i0 + l;

    float a[8];
    #pragma unroll
    for (int n = 0; n < 8; ++n) a[n] = -__expf(A_log[i * 8 + n]);

    const size_t rb = (size_t)b * NS + (size_t)w * CLEN;

    // ---- phase 1: local chunk scan from zero state ----
    float Ap[8], S[8];
    #pragma unroll
    for (int n = 0; n < 8; ++n) { Ap[n] = 1.f; S[n] = 0.f; }
    for (int s = 0; s < CLEN; ++s) {
        const size_t row = rb + s;
        const float xv  = xc[row * D_INNER + i];
        const float dtv = dt[row * D_INNER + i];
        const float* bc = dtbc + row * 64 + DT_RANK;
        #pragma unroll
        for (int n = 0; n < 8; ++n) {
            const float da = __expf(dtv * a[n]);
            S[n]  = da * S[n] + (1.f - da) * bc[n] * xv;
            Ap[n] *= da;
        }
    }
    #pragma unroll
    for (int n = 0; n < 8; ++n) { shA[w][n][l] = Ap[n]; shS[w][n][l] = S[n]; }
    __syncthreads();

    // ---- phase 2: prefix over chunks; thread = (state n = w, lane l) ----
    {
        const int n2 = w;
        float run = 0.f;
        #pragma unroll
        for (int c = 0; c < NCH; ++c) {
            const float Ac = shA[c][n2][l];
            const float Sc = shS[c][n2][l];
            shS[c][n2][l] = run;               // exclusive start state for chunk c
            run = Sc + Ac * run;
        }
    }
    __syncthreads();

    // ---- phase 3: replay with correct start state + epilogue ----
    float st[8];
    #pragma unroll
    for (int n = 0; n < 8; ++n) st[n] = shS[w][n][l];
    const float dsk = D_skip[i];
    unsigned short* y3 = (unsigned short*)xz;
    for (int s = 0; s < CLEN; ++s) {
        const size_t row = rb + s;
        const float xv  = xc[row * D_INNER + i];
        const float dtv = dt[row * D_INNER + i];
        const float* bc = dtbc + row * 64 + DT_RANK;
        float accy = 0.f;
        #pragma unroll
        for (int n = 0; n < 8; ++n) {
            const float da = __expf(dtv * a[n]);
            st[n] = da * st[n] + (1.f - da) * bc[n] * xv;
            accy += st[n] * bc[8 + n];
        }
        const float y  = accy + dsk * xv;
        const float zv = xz[row * (2 * D_INNER) + D_INNER + i];
        const float ym = y * (zv * sigmoidf_(zv));
        unsigned short h  = f2bf(ym);
        unsigned short lo = f2bf(ym - bf2f(h));
        unsigned short* d = y3 + row * (size_t)(4 * D_INNER) + i;
        d[0]       = h;
        d[D_INNER] = lo;
    }
}

extern "C" void kernel_launch(void* const* d_in, const int* in_sizes, int n_in,
                              void* d_out, int out_size, void* d_ws, size_t ws_size,
                              hipStream_t stream) {
    const float* x      = (const float*)d_in[0];
    const float* W_in   = (const float*)d_in[1];
    const float* conv_w = (const float*)d_in[2];
    const float* conv_b = (const float*)d_in[3];
    const float* W_x    = (const float*)d_in[4];
    const float* W_dt   = (const float*)d_in[5];
    const float* b_dt   = (const float*)d_in[6];
    const float* A_log  = (const float*)d_in[7];
    const float* D_skip = (const float*)d_in[8];
    const float* W_out  = (const float*)d_in[9];
    float* out = (float*)d_out;

    // Workspace: EXACTLY the round-1 footprint (203,423,744 B, proven <= ws_size).
    char* wsb = (char*)d_ws;
    float* xz   = (float*)(wsb);                    // [8192][3072] f32 (y3 bf16 reuses x-half)
    float* xc   = (float*)(wsb + 100663296);        // [8192][1536] f32
    float* dtbc = (float*)(wsb + 150994944);        // [8192][64]   f32
    float* dtb  = (float*)(wsb + 153092096);        // [8192][1536] f32  (aliased below)
    unsigned short* x3  = (unsigned short*)(wsb + 153092096);  // [8192][1536] hi|lo, dead before dtb
    unsigned short* W3  = (unsigned short*)(wsb + 178257920);  // [3072][768] hi-only, dead before dtb
    unsigned short* Wo3 = (unsigned short*)(wsb + 153092096);  // [768][1536] hi-only, born after dtb dies
    unsigned short* y3  = (unsigned short*)xz;                 // rows @ stride 6144 shorts

    dim3 blk(256);

    // 0) conversions for GEMM1: A = x [hi|lo], B = W_in hi-only
    split2<<<dim3((MROWS * D_MODEL + 255) / 256), blk, 0, stream>>>(x, x3, MROWS, D_MODEL);
    split1<<<dim3((2 * D_INNER * D_MODEL + 255) / 256), blk, 0, stream>>>(W_in, W3, 2 * D_INNER * D_MODEL);

    // 1) xz = x @ W_in^T via MFMA (virtual K' = 2*768)
    gemm_mfma_nt<<<dim3(3072 / 128, MROWS / 128), blk, 0, stream>>>(
        x3, 2 * D_MODEL, W3, D_MODEL, xz, 3072, D_MODEL);

    // 2) depthwise conv + silu -> xc
    conv_silu<<<dim3((MROWS * D_INNER) / 256), blk, 0, stream>>>(xz, conv_w, conv_b, xc);

    // 3) dtbc = xc @ W_x^T  (N=64, K=1536) with fused tanh on cols >= 48
    gemm_nt<2><<<dim3(64 / 64, MROWS / 64), blk, 0, stream>>>(
        xc, W_x, nullptr, dtbc, MROWS, 64, D_INNER, D_INNER, D_INNER, 64);

    // 5) dt = softplus(dt_part @ W_dt^T + b_dt) + 1e-4 — fp32 vector
    gemm_nt<1><<<dim3(D_INNER / 64, MROWS / 64), blk, 0, stream>>>(
        dtbc, W_dt, b_dt, dtb, MROWS, D_INNER, DT_RANK, 64, DT_RANK, D_INNER);

    // 6) chunk-parallel scan + mix epilogue -> y3 (bf16 hi|lo over xz x-half)
    scan_par<<<dim3(NB * (D_INNER / I_TILE)), dim3(512), 0, stream>>>(
        xc, dtb, dtbc, A_log, D_skip, xz);

    // 6.5) W_out hi-only (dtb region now dead)
    split1<<<dim3((D_MODEL * D_INNER + 255) / 256), blk, 0, stream>>>(W_out, Wo3, D_MODEL * D_INNER);

    // 7) out = y @ W_out^T via MFMA (virtual K' = 2*1536)
    gemm_mfma_nt<<<dim3(D_MODEL / 128, MROWS / 128), blk, 0, stream>>>(
        y3, 4 * D_INNER, Wo3, D_INNER, out, D_MODEL, D_INNER);
}